// Round 2
// baseline (308.480 us; speedup 1.0000x reference)
//
#include <hip/hip_runtime.h>

// LSTM decoder: B=1024, H=16, 4H=64 gates, T=128 steps x 16 cells = 2048
// strictly-serial cell evaluations per batch chain. 1 chain = 1 wave =
// 1 SIMD (occupancy structurally pinned; all hiding is intra-wave ILP).
//
// Round-17 = round-16 (208.4us = ~244 cyc/cell, 188 busy) with the two
// v_rcp transcendentals replaced by integer-magic + 3-Newton reciprocal
// (7 full-rate VALU ops each). Hypothesis under test: trans ops occupy
// ~18-31 cyc/inst of the VALU pipe (26-50% of busy time); swapping 2 of
// the 4 for ~14-cyc FMA chains cuts 12-42 cyc/cell.
// Numerics: Newton converges to <=1 ulp (seed err ~5% -> ^8 ~ 1e-11) but
// is not bit-identical to v_rcp; absmax may move off 0.0.
// Domain safety: m = 1+2^z with z bounded (|preact| < ~10, |c_nat| < ~3)
// so m in [1, ~3e4]; no inf/NaN through the magic seed.
//
// Carried: per-lane one-gate mapping relabeled by probed permlane slots;
// 15 v_mul/v_fmac_f32_dpp fused gather-MACs (asm); 3 permlane16/32_swap
// gate exchange; c in exp2-scaled domain; tanh tail fmaf(-ov,ec,ov)*rcp;
// DPP row-sum pred reduction; lazy pred; s-loop unroll x2.

#define B_ 1024
#define A_ 16
#define T_ 128
#define R_ 128
#define H_ 16

typedef unsigned int u32x2 __attribute__((ext_vector_type(2)));

// Broadcast the 4 gate rows to all lanes (slot order probed at init).
__device__ __forceinline__ void gate_xchg(float act, int kp,
                                          float& s0, float& s1,
                                          float& s2, float& s3) {
#if __has_builtin(__builtin_amdgcn_permlane32_swap) && __has_builtin(__builtin_amdgcn_permlane16_swap)
    const unsigned a = __float_as_uint(act);
    const u32x2 pq = __builtin_amdgcn_permlane32_swap(a, a, false, false);
    const u32x2 rs = __builtin_amdgcn_permlane16_swap(pq.x, pq.x, false, false);
    const u32x2 tu = __builtin_amdgcn_permlane16_swap(pq.y, pq.y, false, false);
    s0 = __uint_as_float(rs.x); s1 = __uint_as_float(rs.y);
    s2 = __uint_as_float(tu.x); s3 = __uint_as_float(tu.y);
#else
    s0 = __shfl(act, kp,      64);
    s1 = __shfl(act, kp + 16, 64);
    s2 = __shfl(act, kp + 32, 64);
    s3 = __shfl(act, kp + 48, 64);
#endif
}

// Row-wide sum via DPP rotations: every lane ends with sum over its 16-lane
// row. Direction-agnostic (any consistent rotation gives a complete tree).
__device__ __forceinline__ float row_sum(float m) {
    float pm = m;
    asm("s_nop 1\n\t"
        "v_add_f32_dpp %0, %0, %0 row_ror:8 row_mask:0xf bank_mask:0xf\n\t"
        "s_nop 1\n\t"
        "v_add_f32_dpp %0, %0, %0 row_ror:4 row_mask:0xf bank_mask:0xf\n\t"
        "s_nop 1\n\t"
        "v_add_f32_dpp %0, %0, %0 row_ror:2 row_mask:0xf bank_mask:0xf\n\t"
        "s_nop 1\n\t"
        "v_add_f32_dpp %0, %0, %0 row_ror:1 row_mask:0xf bank_mask:0xf"
        : "+v"(pm));
    return pm;
}

// Full-rate-VALU reciprocal: integer-magic seed (~5% rel err) + 3 Newton
// steps (err squares each step -> ~1e-11 -> rounds to <=1 ulp). 7 VALU ops,
// ~14 cyc issue vs v_rcp's ~18-31 cyc trans occupancy.
// Valid for normal positive m (here m = 1 + 2^z, m in [1, ~3e4]).
__device__ __forceinline__ float fast_rcp(float m) {
    float r = __int_as_float(0x7EF311C3 - __float_as_int(m));
    r = r * fmaf(-m, r, 2.0f);
    r = r * fmaf(-m, r, 2.0f);
    r = r * fmaf(-m, r, 2.0f);
    return r;
}

// One LSTM cell. Macro (not function) so w16[] stays a register array.
// Hazard note: fmaf(hk, w16[0], z0) reads hk and writes asm input z0, so it
// cannot be scheduled out from between hk's def and the asm block -> >=2
// cycles between the v_mul that writes hk and the first DPP read of hk.
#define CELL(xv)                                                              \
    do {                                                                      \
        const float x_ = (xv);                                                \
        float z0 = fmaf(x_, wij, bj);                                         \
        z0 = fmaf(hk, w16[0], z0);                                            \
        float z1, z2, z3;                                                     \
        asm("v_mul_f32_dpp  %1, %4, %6  row_ror:1  row_mask:0xf bank_mask:0xf\n\t" \
            "v_mul_f32_dpp  %2, %4, %7  row_ror:2  row_mask:0xf bank_mask:0xf\n\t" \
            "v_mul_f32_dpp  %3, %4, %8  row_ror:3  row_mask:0xf bank_mask:0xf\n\t" \
            "v_fmac_f32_dpp %0, %4, %9  row_ror:4  row_mask:0xf bank_mask:0xf\n\t" \
            "v_fmac_f32_dpp %1, %4, %10 row_ror:5  row_mask:0xf bank_mask:0xf\n\t" \
            "v_fmac_f32_dpp %2, %4, %11 row_ror:6  row_mask:0xf bank_mask:0xf\n\t" \
            "v_fmac_f32_dpp %3, %4, %12 row_ror:7  row_mask:0xf bank_mask:0xf\n\t" \
            "v_fmac_f32_dpp %0, %4, %13 row_ror:8  row_mask:0xf bank_mask:0xf\n\t" \
            "v_fmac_f32_dpp %1, %4, %14 row_ror:9  row_mask:0xf bank_mask:0xf\n\t" \
            "v_fmac_f32_dpp %2, %4, %15 row_ror:10 row_mask:0xf bank_mask:0xf\n\t" \
            "v_fmac_f32_dpp %3, %4, %16 row_ror:11 row_mask:0xf bank_mask:0xf\n\t" \
            "v_fmac_f32_dpp %0, %4, %17 row_ror:12 row_mask:0xf bank_mask:0xf\n\t" \
            "v_fmac_f32_dpp %1, %4, %18 row_ror:13 row_mask:0xf bank_mask:0xf\n\t" \
            "v_fmac_f32_dpp %2, %4, %19 row_ror:14 row_mask:0xf bank_mask:0xf\n\t" \
            "v_fmac_f32_dpp %3, %4, %20 row_ror:15 row_mask:0xf bank_mask:0xf"     \
            : "+v"(z0), "=&v"(z1), "=&v"(z2), "=&v"(z3)                       \
            : "v"(hk),                                                        \
              "v"(w16[0]),  "v"(w16[1]),  "v"(w16[2]),  "v"(w16[3]),          \
              "v"(w16[4]),  "v"(w16[5]),  "v"(w16[6]),  "v"(w16[7]),          \
              "v"(w16[8]),  "v"(w16[9]),  "v"(w16[10]), "v"(w16[11]),         \
              "v"(w16[12]), "v"(w16[13]), "v"(w16[14]), "v"(w16[15]));        \
        const float z = (z0 + z1) + (z2 + z3);                                \
        const float e   = __builtin_amdgcn_exp2f(z);                          \
        const float sg  = fast_rcp(1.0f + e);                                 \
        const float act = fmaf(aAct, sg, bAct);                               \
        float iv, fv, gg, ov;                                                 \
        gate_xchg(act, kp, iv, fv, gg, ov);                                   \
        c = fmaf(fv, c, iv * gg);                                             \
        const float ec = __builtin_amdgcn_exp2f(c);                           \
        const float rc = fast_rcp(1.0f + ec);                                 \
        const float nm = fmaf(-ov, ec, ov);                                   \
        hk = nm * rc;                                                         \
    } while (0)

__global__ __launch_bounds__(64) void lstm_decoder_kernel(
    const float* __restrict__ y,     // (B,16)
    const float* __restrict__ u,     // (B,128)
    const float* __restrict__ W_ih,  // (64,1)
    const float* __restrict__ W_hh,  // (64,16)
    const float* __restrict__ b_ih,  // (64)
    const float* __restrict__ b_hh,  // (64)
    const float* __restrict__ W_lin, // (1,16)
    const float* __restrict__ b_lin, // (1)
    const float* __restrict__ W_h0,  // (16,128)
    const float* __restrict__ b_h0,  // (16)
    const float* __restrict__ W_c0,  // (16,128)
    const float* __restrict__ b_c0,  // (16)
    float* __restrict__ out)         // (B,144)
{
    const int b  = blockIdx.x;    // batch chain
    const int j  = threadIdx.x;   // lane 0..63
    const int kp = j & 15;        // hidden index this lane carries

    __shared__ float lds_u[R_];
    __shared__ float lds_h[H_];
    __shared__ float lds_c[H_];

    // ---- stage u[b,:] to LDS (coalesced) ----
    lds_u[j]      = u[b * R_ + j];
    lds_u[j + 64] = u[b * R_ + j + 64];
    __syncthreads();

    // ---- h0 / c0 init: lanes 0..15 -> h0[kp], lanes 16..31 -> c0[kp] ----
    if (j < 32) {
        const float* Wr = (j < 16) ? (W_h0 + kp * R_) : (W_c0 + kp * R_);
        float acc = (j < 16) ? b_h0[kp] : b_c0[kp];
        #pragma unroll
        for (int r = 0; r < R_; r += 4) {
            float4 wv = *(const float4*)(Wr + r);
            float4 uv = *(const float4*)(&lds_u[r]);
            acc = fmaf(wv.x, uv.x, acc);
            acc = fmaf(wv.y, uv.y, acc);
            acc = fmaf(wv.z, uv.z, acc);
            acc = fmaf(wv.w, uv.w, acc);
        }
        if (j < 16) lds_h[kp] = acc;
        else        lds_c[kp] = acc;
    }

    // ---- probe 1: DPP row_ror direction ----
    const int probe = __builtin_amdgcn_update_dpp(0, kp, 0x121, 0xF, 0xF, true);
    const bool plus = (probe == ((kp + 1) & 15));

    // ---- probe 2: gate-exchange slot->row mapping; relabel this lane ----
    const float rowf = (float)(j >> 4);
    float pr0, pr1, pr2, pr3;
    gate_xchg(rowf, kp, pr0, pr1, pr2, pr3);
    const int m = (pr0 == rowf) ? 0 : (pr1 == rowf) ? 1 : (pr2 == rowf) ? 2 : 3;

    // ---- per-lane pre-scaled, pre-permuted weights for gate m of kp ----
    const float LOG2E = 1.4426950408889634f;
    const float cK    = -2.0f * LOG2E;           // tanh(c) exp2 scale
    const bool  isg   = (m == 2);
    const float sj    = isg ? (-2.0f * LOG2E) : (-LOG2E);
    const int   grow  = 16 * m + kp;             // row of W_hh for my gate
    float w16[H_];
    #pragma unroll
    for (int r = 0; r < H_; ++r) {
        const int idx = plus ? ((kp + r) & 15) : ((kp - r) & 15);
        w16[r] = sj * W_hh[grow * H_ + idx];
    }
    const float bj  = sj * (b_ih[grow] + b_hh[grow]);
    const float wij = sj * W_ih[grow];
    const float aAct = isg ? 2.0f : ((m == 0) ? cK : 1.0f);
    const float bAct = isg ? -1.0f : 0.0f;
    const float wlk  = W_lin[kp];                // own-lane W_lin element
    const float bl   = b_lin[0];

    __syncthreads();
    float hk = lds_h[kp];          // h[kp], replicated across the 4 rows
    float c  = cK * lds_c[kp];     // c in SCALED domain: c' = cK * c_nat

    float win[A_];
    #pragma unroll
    for (int t = 0; t < A_; ++t) win[t] = y[b * A_ + t];

    float pout0 = 0.f, pout1 = 0.f;
    float pend;                    // h snapshot with a pending pred

    // ---- step 0 (peeled; no pending pred yet) ----
    #pragma unroll
    for (int t = 0; t < A_; ++t) CELL(win[t]);
    #pragma unroll
    for (int t = 0; t < A_ - 1; ++t) win[t] = win[t + 1];
    pend = hk;

    // ---- steps 1..127: pred of step s-1 finished lazily inside step s ----
    #pragma unroll 2
    for (int s = 1; s < T_; ++s) {
        CELL(win[0]);

        // pred of step s-1: row_sum chain hides under cell 0's shadows;
        // its value is only needed at cell t=15 (win[15]).
        const float p = row_sum(pend * wlk) + bl;
        win[A_ - 1] = p;
        if (s - 1 == j)      pout0 = p;
        if (s - 1 == j + 64) pout1 = p;

        #pragma unroll
        for (int t = 1; t < A_; ++t) CELL(win[t]);

        #pragma unroll
        for (int t = 0; t < A_ - 1; ++t) win[t] = win[t + 1];
        pend = hk;
    }

    // ---- final pred (step 127) ----
    {
        const float p = row_sum(pend * wlk) + bl;
        if (T_ - 1 == j + 64) pout1 = p;   // lane 63
    }

    // ---- output: out[b,0:16]=y[b,:], out[b,16+s]=pred_s ----
    if (j < A_) out[b * (A_ + T_) + j] = y[b * A_ + j];
    out[b * (A_ + T_) + A_ + j]      = pout0;
    out[b * (A_ + T_) + A_ + 64 + j] = pout1;
}

extern "C" void kernel_launch(void* const* d_in, const int* in_sizes, int n_in,
                              void* d_out, int out_size, void* d_ws, size_t ws_size,
                              hipStream_t stream) {
    const float* y     = (const float*)d_in[0];
    const float* u     = (const float*)d_in[1];
    const float* W_ih  = (const float*)d_in[2];
    const float* W_hh  = (const float*)d_in[3];
    const float* b_ih  = (const float*)d_in[4];
    const float* b_hh  = (const float*)d_in[5];
    const float* W_lin = (const float*)d_in[6];
    const float* b_lin = (const float*)d_in[7];
    const float* W_h0  = (const float*)d_in[8];
    const float* b_h0  = (const float*)d_in[9];
    const float* W_c0  = (const float*)d_in[10];
    const float* b_c0  = (const float*)d_in[11];
    float* out = (float*)d_out;

    lstm_decoder_kernel<<<B_, 64, 0, stream>>>(
        y, u, W_ih, W_hh, b_ih, b_hh, W_lin, b_lin,
        W_h0, b_h0, W_c0, b_c0, out);
}

// Round 3
// 261.832 us; speedup vs baseline: 1.1782x; 1.1782x over previous
//
#include <hip/hip_runtime.h>

// LSTM decoder: B=1024, H=16, 4H=64 gates, T=128 steps x 16 cells = 2048
// strictly-serial cell evaluations per batch chain. 1 chain = 1 wave =
// 1 SIMD (occupancy structurally pinned; all hiding is intra-wave ILP).
//
// Round-18 = round-16 (208.4us; round-17's Newton-rcp REVERTED: +23%,
// proved the cell is dependency-latency-bound at ~4 cyc/dependent inst,
// not trans-throughput-bound) + PRE-TRANSFORMED WINDOW:
//   win[] was only consumed via z0 = fmaf(win[t], wij, bj), and that
//   transform commutes with the window shift. Keep xw[t] = fmaf(win,wij,bj)
//   instead; shift it identically; only the incoming pred needs a new fma
//   (1/step instead of 16/step). Deletes 15 chain-head FMAs per step and
//   frees their issue slots for the latency-stalled activation tail.
//   Bit-identical numerics (same ops, computed once).
//
// Rejected-by-analysis: 8-way MAC accumulator split (accumulator src2 is
// not read through the DPP network -> no VALU->DPP hazard; distance-4
// round-robin at 2-cyc issue already covers dep latency).
//
// Carried: per-lane one-gate mapping relabeled by probed permlane slots;
// 15 v_mul/v_fmac_f32_dpp fused gather-MACs (asm); 3 permlane16/32_swap
// gate exchange; c in exp2-scaled domain; tanh tail fmaf(-ov,ec,ov)*rcp;
// DPP row-sum pred reduction; lazy pred; s-loop unroll x2.

#define B_ 1024
#define A_ 16
#define T_ 128
#define R_ 128
#define H_ 16

typedef unsigned int u32x2 __attribute__((ext_vector_type(2)));

// Broadcast the 4 gate rows to all lanes (slot order probed at init).
__device__ __forceinline__ void gate_xchg(float act, int kp,
                                          float& s0, float& s1,
                                          float& s2, float& s3) {
#if __has_builtin(__builtin_amdgcn_permlane32_swap) && __has_builtin(__builtin_amdgcn_permlane16_swap)
    const unsigned a = __float_as_uint(act);
    const u32x2 pq = __builtin_amdgcn_permlane32_swap(a, a, false, false);
    const u32x2 rs = __builtin_amdgcn_permlane16_swap(pq.x, pq.x, false, false);
    const u32x2 tu = __builtin_amdgcn_permlane16_swap(pq.y, pq.y, false, false);
    s0 = __uint_as_float(rs.x); s1 = __uint_as_float(rs.y);
    s2 = __uint_as_float(tu.x); s3 = __uint_as_float(tu.y);
#else
    s0 = __shfl(act, kp,      64);
    s1 = __shfl(act, kp + 16, 64);
    s2 = __shfl(act, kp + 32, 64);
    s3 = __shfl(act, kp + 48, 64);
#endif
}

// Row-wide sum via DPP rotations: every lane ends with sum over its 16-lane
// row. Direction-agnostic (any consistent rotation gives a complete tree).
// s_nops required: each dpp-add reads the result of the immediately
// preceding VALU op (2 wait states).
__device__ __forceinline__ float row_sum(float m) {
    float pm = m;
    asm("s_nop 1\n\t"
        "v_add_f32_dpp %0, %0, %0 row_ror:8 row_mask:0xf bank_mask:0xf\n\t"
        "s_nop 1\n\t"
        "v_add_f32_dpp %0, %0, %0 row_ror:4 row_mask:0xf bank_mask:0xf\n\t"
        "s_nop 1\n\t"
        "v_add_f32_dpp %0, %0, %0 row_ror:2 row_mask:0xf bank_mask:0xf\n\t"
        "s_nop 1\n\t"
        "v_add_f32_dpp %0, %0, %0 row_ror:1 row_mask:0xf bank_mask:0xf"
        : "+v"(pm));
    return pm;
}

// One LSTM cell; xz = fmaf(x, wij, bj) precomputed (pre-transformed window).
// Hazard note: fmaf(hk, w16[0], z0) reads hk and writes asm input z0, so it
// cannot be scheduled out from between hk's def and the asm block -> >=2
// cycles between the v_mul that writes hk and the first DPP read of hk.
#define CELL(xz)                                                              \
    do {                                                                      \
        float z0 = fmaf(hk, w16[0], (xz));                                    \
        float z1, z2, z3;                                                     \
        asm("v_mul_f32_dpp  %1, %4, %6  row_ror:1  row_mask:0xf bank_mask:0xf\n\t" \
            "v_mul_f32_dpp  %2, %4, %7  row_ror:2  row_mask:0xf bank_mask:0xf\n\t" \
            "v_mul_f32_dpp  %3, %4, %8  row_ror:3  row_mask:0xf bank_mask:0xf\n\t" \
            "v_fmac_f32_dpp %0, %4, %9  row_ror:4  row_mask:0xf bank_mask:0xf\n\t" \
            "v_fmac_f32_dpp %1, %4, %10 row_ror:5  row_mask:0xf bank_mask:0xf\n\t" \
            "v_fmac_f32_dpp %2, %4, %11 row_ror:6  row_mask:0xf bank_mask:0xf\n\t" \
            "v_fmac_f32_dpp %3, %4, %12 row_ror:7  row_mask:0xf bank_mask:0xf\n\t" \
            "v_fmac_f32_dpp %0, %4, %13 row_ror:8  row_mask:0xf bank_mask:0xf\n\t" \
            "v_fmac_f32_dpp %1, %4, %14 row_ror:9  row_mask:0xf bank_mask:0xf\n\t" \
            "v_fmac_f32_dpp %2, %4, %15 row_ror:10 row_mask:0xf bank_mask:0xf\n\t" \
            "v_fmac_f32_dpp %3, %4, %16 row_ror:11 row_mask:0xf bank_mask:0xf\n\t" \
            "v_fmac_f32_dpp %0, %4, %17 row_ror:12 row_mask:0xf bank_mask:0xf\n\t" \
            "v_fmac_f32_dpp %1, %4, %18 row_ror:13 row_mask:0xf bank_mask:0xf\n\t" \
            "v_fmac_f32_dpp %2, %4, %19 row_ror:14 row_mask:0xf bank_mask:0xf\n\t" \
            "v_fmac_f32_dpp %3, %4, %20 row_ror:15 row_mask:0xf bank_mask:0xf"     \
            : "+v"(z0), "=&v"(z1), "=&v"(z2), "=&v"(z3)                       \
            : "v"(hk),                                                        \
              "v"(w16[0]),  "v"(w16[1]),  "v"(w16[2]),  "v"(w16[3]),          \
              "v"(w16[4]),  "v"(w16[5]),  "v"(w16[6]),  "v"(w16[7]),          \
              "v"(w16[8]),  "v"(w16[9]),  "v"(w16[10]), "v"(w16[11]),         \
              "v"(w16[12]), "v"(w16[13]), "v"(w16[14]), "v"(w16[15]));        \
        const float z = (z0 + z1) + (z2 + z3);                                \
        const float e   = __builtin_amdgcn_exp2f(z);                          \
        const float sg  = __builtin_amdgcn_rcpf(1.0f + e);                    \
        const float act = fmaf(aAct, sg, bAct);                               \
        float iv, fv, gg, ov;                                                 \
        gate_xchg(act, kp, iv, fv, gg, ov);                                   \
        c = fmaf(fv, c, iv * gg);                                             \
        const float ec = __builtin_amdgcn_exp2f(c);                           \
        const float rc = __builtin_amdgcn_rcpf(1.0f + ec);                    \
        const float nm = fmaf(-ov, ec, ov);                                   \
        hk = nm * rc;                                                         \
    } while (0)

__global__ __launch_bounds__(64) void lstm_decoder_kernel(
    const float* __restrict__ y,     // (B,16)
    const float* __restrict__ u,     // (B,128)
    const float* __restrict__ W_ih,  // (64,1)
    const float* __restrict__ W_hh,  // (64,16)
    const float* __restrict__ b_ih,  // (64)
    const float* __restrict__ b_hh,  // (64)
    const float* __restrict__ W_lin, // (1,16)
    const float* __restrict__ b_lin, // (1)
    const float* __restrict__ W_h0,  // (16,128)
    const float* __restrict__ b_h0,  // (16)
    const float* __restrict__ W_c0,  // (16,128)
    const float* __restrict__ b_c0,  // (16)
    float* __restrict__ out)         // (B,144)
{
    const int b  = blockIdx.x;    // batch chain
    const int j  = threadIdx.x;   // lane 0..63
    const int kp = j & 15;        // hidden index this lane carries

    __shared__ float lds_u[R_];
    __shared__ float lds_h[H_];
    __shared__ float lds_c[H_];

    // ---- stage u[b,:] to LDS (coalesced) ----
    lds_u[j]      = u[b * R_ + j];
    lds_u[j + 64] = u[b * R_ + j + 64];
    __syncthreads();

    // ---- h0 / c0 init: lanes 0..15 -> h0[kp], lanes 16..31 -> c0[kp] ----
    if (j < 32) {
        const float* Wr = (j < 16) ? (W_h0 + kp * R_) : (W_c0 + kp * R_);
        float acc = (j < 16) ? b_h0[kp] : b_c0[kp];
        #pragma unroll
        for (int r = 0; r < R_; r += 4) {
            float4 wv = *(const float4*)(Wr + r);
            float4 uv = *(const float4*)(&lds_u[r]);
            acc = fmaf(wv.x, uv.x, acc);
            acc = fmaf(wv.y, uv.y, acc);
            acc = fmaf(wv.z, uv.z, acc);
            acc = fmaf(wv.w, uv.w, acc);
        }
        if (j < 16) lds_h[kp] = acc;
        else        lds_c[kp] = acc;
    }

    // ---- probe 1: DPP row_ror direction ----
    const int probe = __builtin_amdgcn_update_dpp(0, kp, 0x121, 0xF, 0xF, true);
    const bool plus = (probe == ((kp + 1) & 15));

    // ---- probe 2: gate-exchange slot->row mapping; relabel this lane ----
    const float rowf = (float)(j >> 4);
    float pr0, pr1, pr2, pr3;
    gate_xchg(rowf, kp, pr0, pr1, pr2, pr3);
    const int m = (pr0 == rowf) ? 0 : (pr1 == rowf) ? 1 : (pr2 == rowf) ? 2 : 3;

    // ---- per-lane pre-scaled, pre-permuted weights for gate m of kp ----
    const float LOG2E = 1.4426950408889634f;
    const float cK    = -2.0f * LOG2E;           // tanh(c) exp2 scale
    const bool  isg   = (m == 2);
    const float sj    = isg ? (-2.0f * LOG2E) : (-LOG2E);
    const int   grow  = 16 * m + kp;             // row of W_hh for my gate
    float w16[H_];
    #pragma unroll
    for (int r = 0; r < H_; ++r) {
        const int idx = plus ? ((kp + r) & 15) : ((kp - r) & 15);
        w16[r] = sj * W_hh[grow * H_ + idx];
    }
    const float bj  = sj * (b_ih[grow] + b_hh[grow]);
    const float wij = sj * W_ih[grow];
    const float aAct = isg ? 2.0f : ((m == 0) ? cK : 1.0f);
    const float bAct = isg ? -1.0f : 0.0f;
    const float wlk  = W_lin[kp];                // own-lane W_lin element
    const float bl   = b_lin[0];

    __syncthreads();
    float hk = lds_h[kp];          // h[kp], replicated across the 4 rows
    float c  = cK * lds_c[kp];     // c in SCALED domain: c' = cK * c_nat

    // ---- window kept in PRE-TRANSFORMED domain: xw[t] = fmaf(win,wij,bj)
    float xw[A_];
    #pragma unroll
    for (int t = 0; t < A_; ++t) xw[t] = fmaf(y[b * A_ + t], wij, bj);

    float pout0 = 0.f, pout1 = 0.f;
    float pend;                    // h snapshot with a pending pred

    // ---- step 0 (peeled; no pending pred yet) ----
    #pragma unroll
    for (int t = 0; t < A_; ++t) CELL(xw[t]);
    #pragma unroll
    for (int t = 0; t < A_ - 1; ++t) xw[t] = xw[t + 1];
    pend = hk;

    // ---- steps 1..127: pred of step s-1 finished lazily inside step s ----
    #pragma unroll 2
    for (int s = 1; s < T_; ++s) {
        CELL(xw[0]);

        // pred of step s-1: row_sum chain hides under cell 0's shadows;
        // its transformed value is only needed at cell t=15.
        const float p = row_sum(pend * wlk) + bl;
        xw[A_ - 1] = fmaf(p, wij, bj);          // the ONE new fma per step
        if (s - 1 == j)      pout0 = p;
        if (s - 1 == j + 64) pout1 = p;

        #pragma unroll
        for (int t = 1; t < A_; ++t) CELL(xw[t]);

        #pragma unroll
        for (int t = 0; t < A_ - 1; ++t) xw[t] = xw[t + 1];
        pend = hk;
    }

    // ---- final pred (step 127) ----
    {
        const float p = row_sum(pend * wlk) + bl;
        if (T_ - 1 == j + 64) pout1 = p;   // lane 63
    }

    // ---- output: out[b,0:16]=y[b,:], out[b,16+s]=pred_s ----
    if (j < A_) out[b * (A_ + T_) + j] = y[b * A_ + j];
    out[b * (A_ + T_) + A_ + j]      = pout0;
    out[b * (A_ + T_) + A_ + 64 + j] = pout1;
}

extern "C" void kernel_launch(void* const* d_in, const int* in_sizes, int n_in,
                              void* d_out, int out_size, void* d_ws, size_t ws_size,
                              hipStream_t stream) {
    const float* y     = (const float*)d_in[0];
    const float* u     = (const float*)d_in[1];
    const float* W_ih  = (const float*)d_in[2];
    const float* W_hh  = (const float*)d_in[3];
    const float* b_ih  = (const float*)d_in[4];
    const float* b_hh  = (const float*)d_in[5];
    const float* W_lin = (const float*)d_in[6];
    const float* b_lin = (const float*)d_in[7];
    const float* W_h0  = (const float*)d_in[8];
    const float* b_h0  = (const float*)d_in[9];
    const float* W_c0  = (const float*)d_in[10];
    const float* b_c0  = (const float*)d_in[11];
    float* out = (float*)d_out;

    lstm_decoder_kernel<<<B_, 64, 0, stream>>>(
        y, u, W_ih, W_hh, b_ih, b_hh, W_lin, b_lin,
        W_h0, b_h0, W_c0, b_c0, out);
}